// Round 10
// baseline (485.081 us; speedup 1.0000x reference)
//
#include <hip/hip_runtime.h>
#include <stdint.h>

#define N_NODES 100000
#define N_EDGES 3200000
#define DIM 128
#define NPAD 100032   // 1563 * 64
#define NBINS 391     // ceil(100000 / 256) -- 256 nodes per bin
#define NBLK 782      // edge blocks: ceil(3.2M / 4096)
#define BCAP 10176    // bin capacity; mean 8184, +22 sigma
#define EPB 4096      // edges per bin/hist block (16/thread)
#define SLU32 800000  // u32 per 16-dim slice table: 100000 nodes * 8 u32 (32 B)
#define WSTR 140      // LDS row stride in shorts (280 B) -> ~2-way banks, free

typedef short short8 __attribute__((ext_vector_type(8)));
typedef float f32x4 __attribute__((ext_vector_type(4)));
typedef float f32x2 __attribute__((ext_vector_type(2)));

__device__ __forceinline__ short f2bf(float x) {
    uint32_t u = __builtin_bit_cast(uint32_t, x);
    u += 0x7fffu + ((u >> 16) & 1u);   // round-to-nearest-even
    return (short)(u >> 16);
}
__device__ __forceinline__ float bflo(uint32_t p) {
    return __builtin_bit_cast(float, p << 16);
}
__device__ __forceinline__ float bfhi(uint32_t p) {
    return __builtin_bit_cast(float, p & 0xffff0000u);
}
__device__ __forceinline__ uint32_t pack2(float x, float y) {
    return (uint32_t)(uint16_t)f2bf(x) | ((uint32_t)(uint16_t)f2bf(y) << 16);
}
__device__ __forceinline__ f32x2 up2(uint32_t p) {
    return (f32x2){ bflo(p), bfhi(p) };
}

// ---- K1: fused prep: feat->bf16 cast (8 x 16-dim SLICE tables), W^T -----
// featp layout: featp[s][node][8 u32]  (slice s = dims 16s..16s+15, 32 B/row)
__global__ __launch_bounds__(256) void prep_kernel(const float* __restrict__ feat,
                                                   uint32_t* __restrict__ featp,
                                                   const float* __restrict__ w1,
                                                   const float* __restrict__ w2,
                                                   short* __restrict__ w1t,
                                                   short* __restrict__ w2t) {
    int b = blockIdx.x, t = threadIdx.x;
    if (b < 12500) {                       // cast: 3.2M float4s
        int i = b * 256 + t;
        float4 f = ((const float4*)feat)[i];
        int node = i >> 5;                 // 32 float4s per 128-dim row
        int qi = i & 31;                   // which float4 in row (dims 4qi..4qi+3)
        int s = qi >> 2;                   // 16-dim slice
        int w = qi & 3;                    // float4 within slice
        uint32_t* o = &featp[(size_t)s * SLU32 + node * 8 + w * 2];
        o[0] = pack2(f.x, f.y);
        o[1] = pack2(f.z, f.w);
    } else {                               // weight transpose: 16384 elems
        int i = (b - 12500) * 256 + t;
        int k = i >> 7, n = i & 127;
        w1t[n * DIM + k] = f2bf(w1[i]);
        w2t[n * DIM + k] = f2bf(w2[i]);
    }
}

// ---- K2a: per-block bin histogram (no device atomics) -------------------
__global__ __launch_bounds__(256) void hist_kernel(const int* __restrict__ dst,
                                                   int* __restrict__ ghist) {
    __shared__ int hist[NBINS];
    int t = threadIdx.x;
    for (int i = t; i < NBINS; i += 256) hist[i] = 0;
    __syncthreads();
    int e0 = blockIdx.x * EPB;
    int nn = min(EPB, N_EDGES - e0);
    for (int i = t; i < nn; i += 256) atomicAdd(&hist[dst[e0 + i] >> 8], 1);
    __syncthreads();
    for (int b = t; b < NBINS; b += 256)
        ghist[b * NBLK + blockIdx.x] = hist[b];
}

// ---- K2b: per-bin scan over blocks -> deterministic offsets -------------
__global__ __launch_bounds__(1024) void offset_kernel(const int* __restrict__ ghist,
                                                      int* __restrict__ goff,
                                                      int* __restrict__ bincnt) {
    __shared__ int s[1024];
    int b = blockIdx.x, t = threadIdx.x;
    int v = (t < NBLK) ? ghist[b * NBLK + t] : 0;
    s[t] = v;
    __syncthreads();
    for (int d = 1; d < 1024; d <<= 1) {
        int x = (t >= d) ? s[t - d] : 0;
        __syncthreads();
        s[t] += x;
        __syncthreads();
    }
    if (t < NBLK) goff[b * NBLK + t] = s[t] - v;   // exclusive over blocks
    if (t == NBLK - 1) bincnt[b] = s[t];           // bin total
}

// ---- K2c: bin edges by dst>>8, LDS counting-sort, coalesced write-out ---
__global__ __launch_bounds__(256) void bin_kernel(const int* __restrict__ src,
                                                  const int* __restrict__ dst,
                                                  const int* __restrict__ goff,
                                                  uint32_t* __restrict__ binpair) {
    __shared__ int hist[512];
    __shared__ int scanv[512];
    __shared__ int scan256[256];
    __shared__ int gbase[NBINS];
    __shared__ int cursor[NBINS];
    __shared__ uint32_t sorted[EPB];
    __shared__ int saddr[EPB];
    int t = threadIdx.x;
    for (int i = t; i < 512; i += 256) hist[i] = 0;
    __syncthreads();
    int e0 = blockIdx.x * EPB;
    int nn = min(EPB, N_EDGES - e0);
    int d[16];
#pragma unroll
    for (int i = 0; i < 16; i++) {
        int idx = i * 256 + t;
        d[i] = (idx < nn) ? dst[e0 + idx] : -1;
        if (d[i] >= 0) atomicAdd(&hist[d[i] >> 8], 1);
    }
    __syncthreads();
    int h0 = hist[2 * t], h1 = hist[2 * t + 1];
    scan256[t] = h0 + h1;
    __syncthreads();
    for (int dd = 1; dd < 256; dd <<= 1) {
        int v = (t >= dd) ? scan256[t - dd] : 0;
        __syncthreads();
        scan256[t] += v;
        __syncthreads();
    }
    int pairExcl = scan256[t] - (h0 + h1);
    scanv[2 * t] = pairExcl;
    scanv[2 * t + 1] = pairExcl + h0;
    for (int b = t; b < NBINS; b += 256) {
        gbase[b] = goff[b * NBLK + blockIdx.x];    // deterministic, no atomic
        cursor[b] = 0;
    }
    __syncthreads();
#pragma unroll
    for (int i = 0; i < 16; i++) {
        if (d[i] >= 0) {
            int b = d[i] >> 8;
            int slot = atomicAdd(&cursor[b], 1);
            int p = scanv[b] + slot;
            int g = gbase[b] + slot;
            int e = e0 + i * 256 + t;
            sorted[p] = (uint32_t)src[e] | ((uint32_t)(d[i] & 255) << 24);
            saddr[p] = (g < BCAP) ? (b * BCAP + g) : -1;
        }
    }
    __syncthreads();
    for (int i = t; i < nn; i += 256) {
        int a = saddr[i];
        if (a >= 0) binpair[a] = sorted[i];
    }
}

// ---- K3: per-bin counting sort -> CSR (1024 thr, LDS-staged coalesced) --
__global__ __launch_bounds__(1024) void csr_kernel(const int* __restrict__ bincnt,
                                                   const uint32_t* __restrict__ binpair,
                                                   int* __restrict__ rowptr,
                                                   int* __restrict__ csr) {
    __shared__ int hist[256];
    __shared__ int cursor[256];
    __shared__ int sc[256];
    __shared__ int red[256];
    __shared__ int binbase_s;
    __shared__ int sorted_s[BCAP];
    int b = blockIdx.x;
    int t = threadIdx.x;
    if (t < 256) {
        int partial = 0;
        for (int j = t; j < b; j += 256) partial += min(bincnt[j], BCAP);
        red[t] = partial;
        hist[t] = 0;
    }
    __syncthreads();
    for (int dd = 128; dd > 0; dd >>= 1) {
        if (t < dd) red[t] += red[t + dd];
        __syncthreads();
    }
    if (t == 0) binbase_s = red[0];
    __syncthreads();
    int binbase = binbase_s;
    int cntb = min(bincnt[b], BCAP);
    const uint32_t* pairs = binpair + (size_t)b * BCAP;
    for (int i = t; i < cntb; i += 1024)
        atomicAdd(&hist[pairs[i] >> 24], 1);
    __syncthreads();
    int val = 0;
    if (t < 256) { val = hist[t]; sc[t] = val; }
    __syncthreads();
    for (int dd = 1; dd < 256; dd <<= 1) {
        int addv = (t < 256 && t >= dd) ? sc[t - dd] : 0;
        __syncthreads();
        if (t < 256) sc[t] += addv;
        __syncthreads();
    }
    if (t < 256) {
        int excl = sc[t] - val;
        rowptr[(b << 8) + t] = binbase + excl;
        cursor[t] = excl;
    }
    __syncthreads();
    for (int i = t; i < cntb; i += 1024) {
        uint32_t p = pairs[i];
        int s2 = atomicAdd(&cursor[p >> 24], 1);
        sorted_s[s2] = (int)(p & 0x00FFFFFFu);
    }
    __syncthreads();
    for (int i = t; i < cntb; i += 1024)
        csr[binbase + i] = sorted_s[i];
}

// ---- K4: XCD-pinned slice gather. slice s = blockIdx&7 -> XCD s ---------
// Each XCD's 3.2 MB slice table stays L2-resident; csr/hbf streams are
// nontemporal so they don't evict it. 4 lanes x 8 B per edge row-slice.
__global__ __launch_bounds__(512) void gather_kernel(const uint32_t* __restrict__ featp,
                                                     const int* __restrict__ rowptr,
                                                     const int* __restrict__ csr,
                                                     const float* __restrict__ eps,
                                                     uint32_t* __restrict__ hbf) {
    int s = blockIdx.x & 7;                 // dim-slice == XCD (round-robin)
    int g = blockIdx.x >> 3;                // node group (8 nodes, 8 waves)
    int wave = threadIdx.x >> 6;
    int wid = g * 8 + wave;
    int lane = threadIdx.x & 63;
    int egrp = lane >> 2;                   // edge group 0..15
    int col4 = lane & 3;                    // 8 B column within 32 B row
    const uint32_t* fp = featp + (size_t)s * SLU32;
    if (wid >= N_NODES) {                   // padding rows (nodes 100000..100031)
        if (wid < NPAD && lane < 8) hbf[wid * 64 + s * 8 + lane] = 0;
        return;
    }
    float e1 = 1.0f + eps[0];
    uint2 sf = *(const uint2*)&fp[wid * 8 + col4 * 2];   // self row-slice
    f32x2 A01 = (f32x2){0.f, 0.f}, A23 = (f32x2){0.f, 0.f};
    int start = rowptr[wid], end = rowptr[wid + 1];
    for (int base = start; base < end; base += 64) {
        int m = min(64, end - base);
        int u = 0;
        if (lane < m) u = __builtin_nontemporal_load(&csr[base + lane]);
        int j = 0;
        for (; j + 16 <= m; j += 16) {      // 16 edges per dwordx2 instruction
            int idx = __shfl(u, j + egrp);
            uint2 q = *(const uint2*)&fp[idx * 8 + col4 * 2];
            A01 += up2(q.x); A23 += up2(q.y);
        }
        if (j < m) {                        // masked tail (1..15 edges)
            int p = j + egrp, mm = m - 1;
            int idx = __shfl(u, min(p, mm));
            uint2 q = *(const uint2*)&fp[idx * 8 + col4 * 2];
            if (p < m) { A01 += up2(q.x); A23 += up2(q.y); }
        }
    }
    // reduce across the 16 edge groups (lane bits 2..6)
    float a0 = A01.x, a1 = A01.y, a2 = A23.x, a3 = A23.y;
    a0 += __shfl_xor(a0, 4);  a1 += __shfl_xor(a1, 4);
    a2 += __shfl_xor(a2, 4);  a3 += __shfl_xor(a3, 4);
    a0 += __shfl_xor(a0, 8);  a1 += __shfl_xor(a1, 8);
    a2 += __shfl_xor(a2, 8);  a3 += __shfl_xor(a3, 8);
    a0 += __shfl_xor(a0, 16); a1 += __shfl_xor(a1, 16);
    a2 += __shfl_xor(a2, 16); a3 += __shfl_xor(a3, 16);
    a0 += __shfl_xor(a0, 32); a1 += __shfl_xor(a1, 32);
    a2 += __shfl_xor(a2, 32); a3 += __shfl_xor(a3, 32);
    if (egrp == 0) {                        // lanes 0-3 store 32 B slice
        a0 += e1 * bflo(sf.x); a1 += e1 * bfhi(sf.x);
        a2 += e1 * bflo(sf.y); a3 += e1 * bfhi(sf.y);
        unsigned long long wv = (unsigned long long)pack2(a0, a1)
                              | ((unsigned long long)pack2(a2, a3) << 32);
        __builtin_nontemporal_store(wv,
            (unsigned long long*)&hbf[wid * 64 + s * 8 + col4 * 2]);
    }
}

// ---- K5: fused 2-layer MLP; weights staged ONCE in LDS, 8 indep waves ---
// 256 blocks x 512 thr, 1 block/CU. LDS: 2x35840 (weights) + 8x4480 (h1)
__global__ __launch_bounds__(512) void mlp_kernel(const short* __restrict__ hbf,
                                                  const short* __restrict__ w1t,
                                                  const short* __restrict__ w2t,
                                                  const float* __restrict__ b1,
                                                  const float* __restrict__ b2,
                                                  float* __restrict__ out) {
    __shared__ __align__(16) short w1s[128 * WSTR];
    __shared__ __align__(16) short w2s[128 * WSTR];
    __shared__ __align__(16) short h1s[8][16 * WSTR];
    const int t = threadIdx.x;
    // stage both weight tables into LDS (once per block)
    for (int c = t; c < 2048; c += 512) {          // 2048 short8 chunks/table
        int row = c >> 4, cp = c & 15;
        *(short8*)&w1s[row * WSTR + cp * 8] = *(const short8*)&w1t[row * DIM + cp * 8];
        *(short8*)&w2s[row * WSTR + cp * 8] = *(const short8*)&w2t[row * DIM + cp * 8];
    }
    const int wave = t >> 6;
    const int lane = t & 63;
    const int l15 = lane & 15;
    const int quad = lane >> 4;
    short* h1w = &h1s[wave][0];

    float b1v[8], b2v[8];
#pragma unroll
    for (int n = 0; n < 8; n++) {
        b1v[n] = b1[n * 16 + l15];
        b2v[n] = b2[n * 16 + l15];
    }
    __syncthreads();   // weights staged; waves independent from here on

    const int ngroups = NPAD / 16;                 // 6252 16-row groups
    for (int g = blockIdx.x * 8 + wave; g < ngroups; g += gridDim.x * 8) {
        int row0 = g * 16;
        f32x4 acc[8];
#pragma unroll
        for (int n = 0; n < 8; n++) acc[n] = (f32x4){0.f, 0.f, 0.f, 0.f};
#pragma unroll
        for (int kb = 0; kb < DIM; kb += 32) {
            short8 a = *(const short8*)&hbf[(row0 + l15) * DIM + kb + quad * 8];
#pragma unroll
            for (int n = 0; n < 8; n++) {
                short8 b = *(const short8*)&w1s[(n * 16 + l15) * WSTR + kb + quad * 8];
                acc[n] = __builtin_amdgcn_mfma_f32_16x16x32_bf16(a, b, acc[n], 0, 0, 0);
            }
        }
#pragma unroll
        for (int n = 0; n < 8; n++) {
#pragma unroll
            for (int r = 0; r < 4; r++) {
                float v = acc[n][r] + b1v[n];
                v = v > 0.f ? v : 0.f;
                h1w[(quad * 4 + r) * WSTR + n * 16 + l15] = f2bf(v);
            }
        }
        // same-wave LDS RAW: compiler inserts lgkmcnt wait (no barrier needed)
        f32x4 acc2[8];
#pragma unroll
        for (int n = 0; n < 8; n++) acc2[n] = (f32x4){0.f, 0.f, 0.f, 0.f};
#pragma unroll
        for (int kb = 0; kb < DIM; kb += 32) {
            short8 a2 = *(const short8*)&h1w[l15 * WSTR + kb + quad * 8];
#pragma unroll
            for (int n = 0; n < 8; n++) {
                short8 b = *(const short8*)&w2s[(n * 16 + l15) * WSTR + kb + quad * 8];
                acc2[n] = __builtin_amdgcn_mfma_f32_16x16x32_bf16(a2, b, acc2[n], 0, 0, 0);
            }
        }
#pragma unroll
        for (int n = 0; n < 8; n++) {
#pragma unroll
            for (int r = 0; r < 4; r++) {
                int row = row0 + quad * 4 + r;
                if (row < N_NODES)
                    out[row * DIM + n * 16 + l15] = acc2[n][r] + b2v[n];
            }
        }
    }
}

extern "C" void kernel_launch(void* const* d_in, const int* in_sizes, int n_in,
                              void* d_out, int out_size, void* d_ws, size_t ws_size,
                              hipStream_t stream) {
    const float* feat = (const float*)d_in[0];
    const int* src    = (const int*)d_in[1];
    const int* dst    = (const int*)d_in[2];
    const float* eps  = (const float*)d_in[3];
    const float* W1   = (const float*)d_in[4];
    const float* b1   = (const float*)d_in[5];
    const float* W2   = (const float*)d_in[6];
    const float* b2   = (const float*)d_in[7];
    float* out = (float*)d_out;

    char* ws = (char*)d_ws;
    int*      bincnt  = (int*)ws;                          //     1,564 B -> 2,048
    int*      rowptr  = (int*)(ws + 2048);                 //   401,408 B
    int*      csr     = (int*)(ws + 403456);               // 12,800,000 B
    uint32_t* binpair = (uint32_t*)(ws + 13203456);        // 15,915,264 B (391 x 10176 x 4)
    uint32_t* featp   = (uint32_t*)(ws + 29118720);        // 25,600,000 B (8 slice tables)
    uint32_t* hbf     = (uint32_t*)(ws + 54718720);        // 25,608,192 B
    short*    w1t     = (short*)(ws + 80326912);           //     32,768 B
    short*    w2t     = (short*)(ws + 80359680);           // ends 80,392,448 B
    // ghist/goff alias the hbf region (dead until gather; 2 x 1,223,048 B)
    int*      ghist   = (int*)(ws + 54718720);
    int*      goff    = (int*)(ws + 54718720 + 1223168);

    prep_kernel<<<12564, 256, 0, stream>>>(feat, featp, W1, W2, w1t, w2t);
    hist_kernel<<<NBLK, 256, 0, stream>>>(dst, ghist);
    offset_kernel<<<NBINS, 1024, 0, stream>>>(ghist, goff, bincnt);
    bin_kernel<<<NBLK, 256, 0, stream>>>(src, dst, goff, binpair);
    csr_kernel<<<NBINS, 1024, 0, stream>>>(bincnt, binpair, rowptr, csr);
    gather_kernel<<<(NPAD / 8) * 8, 512, 0, stream>>>(featp, rowptr, csr, eps, hbf);
    mlp_kernel<<<256, 512, 0, stream>>>((const short*)hbf, w1t, w2t, b1, b2, out);
}

// Round 12
// 376.314 us; speedup vs baseline: 1.2890x; 1.2890x over previous
//
#include <hip/hip_runtime.h>
#include <stdint.h>

#define N_NODES 100000
#define N_EDGES 3200000
#define DIM 128
#define NPAD 100032   // 1563 * 64
#define NBINS 391     // ceil(100000 / 256) -- 256 nodes per bin
#define NBLK 782      // edge blocks: ceil(3.2M / 4096)
#define BCAP 10176    // bin capacity; mean 8184, +22 sigma
#define EPB 4096      // edges per bin/hist block (16/thread)
#define SLU32 800000  // u32 per 16-dim slice table: 100000 nodes * 8 u32 (32 B)
#define CSRCAP 11264  // LDS edge-stage capacity: mean 8192 + 34 sigma
#define WSTR 140      // LDS row stride in shorts (280 B) -> ~2-way banks, free

typedef short short8 __attribute__((ext_vector_type(8)));
typedef float f32x4 __attribute__((ext_vector_type(4)));
typedef float f32x2 __attribute__((ext_vector_type(2)));
typedef unsigned int u32x4 __attribute__((ext_vector_type(4)));

__device__ __forceinline__ short f2bf(float x) {
    uint32_t u = __builtin_bit_cast(uint32_t, x);
    u += 0x7fffu + ((u >> 16) & 1u);   // round-to-nearest-even
    return (short)(u >> 16);
}
__device__ __forceinline__ float bflo(uint32_t p) {
    return __builtin_bit_cast(float, p << 16);
}
__device__ __forceinline__ float bfhi(uint32_t p) {
    return __builtin_bit_cast(float, p & 0xffff0000u);
}
__device__ __forceinline__ uint32_t pack2(float x, float y) {
    return (uint32_t)(uint16_t)f2bf(x) | ((uint32_t)(uint16_t)f2bf(y) << 16);
}
__device__ __forceinline__ f32x2 up2(uint32_t p) {
    return (f32x2){ bflo(p), bfhi(p) };
}

// ---- K1: fused prep: feat->bf16 cast (8 x 16-dim SLICE tables), W^T -----
// featp layout: featp[s][node][8 u32]  (slice s = dims 16s..16s+15, 32 B/row)
__global__ __launch_bounds__(256) void prep_kernel(const float* __restrict__ feat,
                                                   uint32_t* __restrict__ featp,
                                                   const float* __restrict__ w1,
                                                   const float* __restrict__ w2,
                                                   short* __restrict__ w1t,
                                                   short* __restrict__ w2t) {
    int b = blockIdx.x, t = threadIdx.x;
    if (b < 12500) {                       // cast: 3.2M float4s
        int i = b * 256 + t;
        float4 f = ((const float4*)feat)[i];
        int node = i >> 5;                 // 32 float4s per 128-dim row
        int qi = i & 31;                   // which float4 in row (dims 4qi..4qi+3)
        int s = qi >> 2;                   // 16-dim slice
        int w = qi & 3;                    // float4 within slice
        uint32_t* o = &featp[(size_t)s * SLU32 + node * 8 + w * 2];
        o[0] = pack2(f.x, f.y);
        o[1] = pack2(f.z, f.w);
    } else {                               // weight transpose: 16384 elems
        int i = (b - 12500) * 256 + t;
        int k = i >> 7, n = i & 127;
        w1t[n * DIM + k] = f2bf(w1[i]);
        w2t[n * DIM + k] = f2bf(w2[i]);
    }
}

// ---- K2a: per-block bin histogram (no device atomics) -------------------
__global__ __launch_bounds__(256) void hist_kernel(const int* __restrict__ dst,
                                                   int* __restrict__ ghist) {
    __shared__ int hist[NBINS];
    int t = threadIdx.x;
    for (int i = t; i < NBINS; i += 256) hist[i] = 0;
    __syncthreads();
    int e0 = blockIdx.x * EPB;
    int nn = min(EPB, N_EDGES - e0);
    for (int i = t; i < nn; i += 256) atomicAdd(&hist[dst[e0 + i] >> 8], 1);
    __syncthreads();
    for (int b = t; b < NBINS; b += 256)
        ghist[b * NBLK + blockIdx.x] = hist[b];
}

// ---- K2b: per-bin scan over blocks -> deterministic offsets -------------
__global__ __launch_bounds__(1024) void offset_kernel(const int* __restrict__ ghist,
                                                      int* __restrict__ goff,
                                                      int* __restrict__ bincnt) {
    __shared__ int s[1024];
    int b = blockIdx.x, t = threadIdx.x;
    int v = (t < NBLK) ? ghist[b * NBLK + t] : 0;
    s[t] = v;
    __syncthreads();
    for (int d = 1; d < 1024; d <<= 1) {
        int x = (t >= d) ? s[t - d] : 0;
        __syncthreads();
        s[t] += x;
        __syncthreads();
    }
    if (t < NBLK) goff[b * NBLK + t] = s[t] - v;   // exclusive over blocks
    if (t == NBLK - 1) bincnt[b] = s[t];           // bin total
}

// ---- K2c: bin edges by dst>>8, LDS counting-sort, coalesced write-out ---
__global__ __launch_bounds__(256) void bin_kernel(const int* __restrict__ src,
                                                  const int* __restrict__ dst,
                                                  const int* __restrict__ goff,
                                                  uint32_t* __restrict__ binpair) {
    __shared__ int hist[512];
    __shared__ int scanv[512];
    __shared__ int scan256[256];
    __shared__ int gbase[NBINS];
    __shared__ int cursor[NBINS];
    __shared__ uint32_t sorted[EPB];
    __shared__ int saddr[EPB];
    int t = threadIdx.x;
    for (int i = t; i < 512; i += 256) hist[i] = 0;
    __syncthreads();
    int e0 = blockIdx.x * EPB;
    int nn = min(EPB, N_EDGES - e0);
    int d[16];
#pragma unroll
    for (int i = 0; i < 16; i++) {
        int idx = i * 256 + t;
        d[i] = (idx < nn) ? dst[e0 + idx] : -1;
        if (d[i] >= 0) atomicAdd(&hist[d[i] >> 8], 1);
    }
    __syncthreads();
    int h0 = hist[2 * t], h1 = hist[2 * t + 1];
    scan256[t] = h0 + h1;
    __syncthreads();
    for (int dd = 1; dd < 256; dd <<= 1) {
        int v = (t >= dd) ? scan256[t - dd] : 0;
        __syncthreads();
        scan256[t] += v;
        __syncthreads();
    }
    int pairExcl = scan256[t] - (h0 + h1);
    scanv[2 * t] = pairExcl;
    scanv[2 * t + 1] = pairExcl + h0;
    for (int b = t; b < NBINS; b += 256) {
        gbase[b] = goff[b * NBLK + blockIdx.x];    // deterministic, no atomic
        cursor[b] = 0;
    }
    __syncthreads();
#pragma unroll
    for (int i = 0; i < 16; i++) {
        if (d[i] >= 0) {
            int b = d[i] >> 8;
            int slot = atomicAdd(&cursor[b], 1);
            int p = scanv[b] + slot;
            int g = gbase[b] + slot;
            int e = e0 + i * 256 + t;
            sorted[p] = (uint32_t)src[e] | ((uint32_t)(d[i] & 255) << 24);
            saddr[p] = (g < BCAP) ? (b * BCAP + g) : -1;
        }
    }
    __syncthreads();
    for (int i = t; i < nn; i += 256) {
        int a = saddr[i];
        if (a >= 0) binpair[a] = sorted[i];
    }
}

// ---- K3: per-bin counting sort -> CSR (1024 thr, LDS-staged coalesced) --
__global__ __launch_bounds__(1024) void csr_kernel(const int* __restrict__ bincnt,
                                                   const uint32_t* __restrict__ binpair,
                                                   int* __restrict__ rowptr,
                                                   int* __restrict__ csr) {
    __shared__ int hist[256];
    __shared__ int cursor[256];
    __shared__ int sc[256];
    __shared__ int red[256];
    __shared__ int binbase_s;
    __shared__ int sorted_s[BCAP];
    int b = blockIdx.x;
    int t = threadIdx.x;
    if (t < 256) {
        int partial = 0;
        for (int j = t; j < b; j += 256) partial += min(bincnt[j], BCAP);
        red[t] = partial;
        hist[t] = 0;
    }
    __syncthreads();
    for (int dd = 128; dd > 0; dd >>= 1) {
        if (t < dd) red[t] += red[t + dd];
        __syncthreads();
    }
    if (t == 0) binbase_s = red[0];
    __syncthreads();
    int binbase = binbase_s;
    int cntb = min(bincnt[b], BCAP);
    const uint32_t* pairs = binpair + (size_t)b * BCAP;
    for (int i = t; i < cntb; i += 1024)
        atomicAdd(&hist[pairs[i] >> 24], 1);
    __syncthreads();
    int val = 0;
    if (t < 256) { val = hist[t]; sc[t] = val; }
    __syncthreads();
    for (int dd = 1; dd < 256; dd <<= 1) {
        int addv = (t < 256 && t >= dd) ? sc[t - dd] : 0;
        __syncthreads();
        if (t < 256) sc[t] += addv;
        __syncthreads();
    }
    if (t < 256) {
        int excl = sc[t] - val;
        rowptr[(b << 8) + t] = binbase + excl;
        cursor[t] = excl;
    }
    __syncthreads();
    for (int i = t; i < cntb; i += 1024) {
        uint32_t p = pairs[i];
        int s2 = atomicAdd(&cursor[p >> 24], 1);
        sorted_s[s2] = (int)(p & 0x00FFFFFFu);
    }
    __syncthreads();
    for (int i = t; i < cntb; i += 1024)
        csr[binbase + i] = sorted_s[i];
}

// ---- K4: XCD-pinned slice gather, 2 lanes/node, LDS-staged edge lists ---
// block = (bin g, slice s=blockIdx&7). Slice table 3.2 MB stays L2-resident
// on its XCD; csr segment staged to LDS coalesced; lane owns 8 dims ->
// NO cross-lane reduce. 16 B dwordx4 loads.
__global__ __launch_bounds__(512) void gather_kernel(const uint32_t* __restrict__ featp,
                                                     const int* __restrict__ rowptr,
                                                     const int* __restrict__ csr,
                                                     const float* __restrict__ eps,
                                                     uint32_t* __restrict__ hbf) {
    __shared__ int ecsr[CSRCAP];
    __shared__ int rp_s[257];
    int s = blockIdx.x & 7;                 // dim-slice == XCD (round-robin)
    int g = blockIdx.x >> 3;                // bin: nodes g*256 .. g*256+255
    int t = threadIdx.x;
    int n0 = g * 256;
    for (int i = t; i < 257; i += 512)
        rp_s[i] = rowptr[min(n0 + i, N_NODES)];
    __syncthreads();
    int base0 = rp_s[0];
    int span = min(rp_s[256] - base0, CSRCAP);
    for (int i = t; i < span; i += 512)
        ecsr[i] = __builtin_nontemporal_load(&csr[base0 + i]);
    __syncthreads();

    const uint32_t* fp = featp + (size_t)s * SLU32;
    int lane = t & 63;
    int wave = t >> 6;
    int half = lane & 1;                    // which 16 B of the 32 B row-slice
    int node_l = wave * 32 + (lane >> 1);   // 0..255 within bin
    int node = n0 + node_l;
    float e1 = 1.0f + eps[0];

    int deg = 0, ebase = 0;
    if (node < N_NODES) {
        ebase = rp_s[node_l] - base0;
        int dend = rp_s[node_l + 1] - base0;
        deg = min(dend, span) - min(ebase, span);
        ebase = min(ebase, span);
    }
    // wave-max degree (uniform loop bound, per-lane predication)
    int wmax = deg;
    wmax = max(wmax, __shfl_xor(wmax, 2));
    wmax = max(wmax, __shfl_xor(wmax, 4));
    wmax = max(wmax, __shfl_xor(wmax, 8));
    wmax = max(wmax, __shfl_xor(wmax, 16));
    wmax = max(wmax, __shfl_xor(wmax, 32));

    f32x2 A01 = (f32x2){0.f, 0.f}, A23 = (f32x2){0.f, 0.f};
    f32x2 A45 = (f32x2){0.f, 0.f}, A67 = (f32x2){0.f, 0.f};
    for (int k = 0; k < wmax; k++) {
        if (k < deg) {
            int idx = ecsr[ebase + k];
            uint4 q = *(const uint4*)&fp[idx * 8 + half * 4];
            A01 += up2(q.x); A23 += up2(q.y);
            A45 += up2(q.z); A67 += up2(q.w);
        }
    }
    if (node < N_NODES) {
        uint4 sf = *(const uint4*)&fp[node * 8 + half * 4];
        A01.x += e1 * bflo(sf.x); A01.y += e1 * bfhi(sf.x);
        A23.x += e1 * bflo(sf.y); A23.y += e1 * bfhi(sf.y);
        A45.x += e1 * bflo(sf.z); A45.y += e1 * bfhi(sf.z);
        A67.x += e1 * bflo(sf.w); A67.y += e1 * bfhi(sf.w);
        u32x4 w;
        w.x = pack2(A01.x, A01.y); w.y = pack2(A23.x, A23.y);
        w.z = pack2(A45.x, A45.y); w.w = pack2(A67.x, A67.y);
        __builtin_nontemporal_store(w,
            (u32x4*)&hbf[node * 64 + s * 8 + half * 4]);
    } else if (node < NPAD) {
        u32x4 z = (u32x4){0, 0, 0, 0};
        __builtin_nontemporal_store(z,
            (u32x4*)&hbf[node * 64 + s * 8 + half * 4]);
    }
}

// ---- K5: fused 2-layer MLP; weights staged ONCE in LDS, 8 indep waves ---
// 256 blocks x 512 thr, 1 block/CU. LDS: 2x35840 (weights) + 8x4480 (h1)
__global__ __launch_bounds__(512) void mlp_kernel(const short* __restrict__ hbf,
                                                  const short* __restrict__ w1t,
                                                  const short* __restrict__ w2t,
                                                  const float* __restrict__ b1,
                                                  const float* __restrict__ b2,
                                                  float* __restrict__ out) {
    __shared__ __align__(16) short w1s[128 * WSTR];
    __shared__ __align__(16) short w2s[128 * WSTR];
    __shared__ __align__(16) short h1s[8][16 * WSTR];
    const int t = threadIdx.x;
    // stage both weight tables into LDS (once per block)
    for (int c = t; c < 2048; c += 512) {          // 2048 short8 chunks/table
        int row = c >> 4, cp = c & 15;
        *(short8*)&w1s[row * WSTR + cp * 8] = *(const short8*)&w1t[row * DIM + cp * 8];
        *(short8*)&w2s[row * WSTR + cp * 8] = *(const short8*)&w2t[row * DIM + cp * 8];
    }
    const int wave = t >> 6;
    const int lane = t & 63;
    const int l15 = lane & 15;
    const int quad = lane >> 4;
    short* h1w = &h1s[wave][0];

    float b1v[8], b2v[8];
#pragma unroll
    for (int n = 0; n < 8; n++) {
        b1v[n] = b1[n * 16 + l15];
        b2v[n] = b2[n * 16 + l15];
    }
    __syncthreads();   // weights staged; waves independent from here on

    const int ngroups = NPAD / 16;                 // 6252 16-row groups
    for (int g = blockIdx.x * 8 + wave; g < ngroups; g += gridDim.x * 8) {
        int row0 = g * 16;
        f32x4 acc[8];
#pragma unroll
        for (int n = 0; n < 8; n++) acc[n] = (f32x4){0.f, 0.f, 0.f, 0.f};
#pragma unroll
        for (int kb = 0; kb < DIM; kb += 32) {
            short8 a = *(const short8*)&hbf[(row0 + l15) * DIM + kb + quad * 8];
#pragma unroll
            for (int n = 0; n < 8; n++) {
                short8 b = *(const short8*)&w1s[(n * 16 + l15) * WSTR + kb + quad * 8];
                acc[n] = __builtin_amdgcn_mfma_f32_16x16x32_bf16(a, b, acc[n], 0, 0, 0);
            }
        }
#pragma unroll
        for (int n = 0; n < 8; n++) {
#pragma unroll
            for (int r = 0; r < 4; r++) {
                float v = acc[n][r] + b1v[n];
                v = v > 0.f ? v : 0.f;
                h1w[(quad * 4 + r) * WSTR + n * 16 + l15] = f2bf(v);
            }
        }
        // same-wave LDS RAW: compiler inserts lgkmcnt wait (no barrier needed)
        f32x4 acc2[8];
#pragma unroll
        for (int n = 0; n < 8; n++) acc2[n] = (f32x4){0.f, 0.f, 0.f, 0.f};
#pragma unroll
        for (int kb = 0; kb < DIM; kb += 32) {
            short8 a2 = *(const short8*)&h1w[l15 * WSTR + kb + quad * 8];
#pragma unroll
            for (int n = 0; n < 8; n++) {
                short8 b = *(const short8*)&w2s[(n * 16 + l15) * WSTR + kb + quad * 8];
                acc2[n] = __builtin_amdgcn_mfma_f32_16x16x32_bf16(a2, b, acc2[n], 0, 0, 0);
            }
        }
#pragma unroll
        for (int n = 0; n < 8; n++) {
#pragma unroll
            for (int r = 0; r < 4; r++) {
                int row = row0 + quad * 4 + r;
                if (row < N_NODES)
                    out[row * DIM + n * 16 + l15] = acc2[n][r] + b2v[n];
            }
        }
    }
}

extern "C" void kernel_launch(void* const* d_in, const int* in_sizes, int n_in,
                              void* d_out, int out_size, void* d_ws, size_t ws_size,
                              hipStream_t stream) {
    const float* feat = (const float*)d_in[0];
    const int* src    = (const int*)d_in[1];
    const int* dst    = (const int*)d_in[2];
    const float* eps  = (const float*)d_in[3];
    const float* W1   = (const float*)d_in[4];
    const float* b1   = (const float*)d_in[5];
    const float* W2   = (const float*)d_in[6];
    const float* b2   = (const float*)d_in[7];
    float* out = (float*)d_out;

    char* ws = (char*)d_ws;
    int*      bincnt  = (int*)ws;                          //     1,564 B -> 2,048
    int*      rowptr  = (int*)(ws + 2048);                 //   401,408 B
    int*      csr     = (int*)(ws + 403456);               // 12,800,000 B
    uint32_t* binpair = (uint32_t*)(ws + 13203456);        // 15,915,264 B (391 x 10176 x 4)
    uint32_t* featp   = (uint32_t*)(ws + 29118720);        // 25,600,000 B (8 slice tables)
    uint32_t* hbf     = (uint32_t*)(ws + 54718720);        // 25,608,192 B
    short*    w1t     = (short*)(ws + 80326912);           //     32,768 B
    short*    w2t     = (short*)(ws + 80359680);           // ends 80,392,448 B
    // ghist/goff alias the hbf region (dead until gather; 2 x 1,223,048 B)
    int*      ghist   = (int*)(ws + 54718720);
    int*      goff    = (int*)(ws + 54718720 + 1223168);

    prep_kernel<<<12564, 256, 0, stream>>>(feat, featp, W1, W2, w1t, w2t);
    hist_kernel<<<NBLK, 256, 0, stream>>>(dst, ghist);
    offset_kernel<<<NBINS, 1024, 0, stream>>>(ghist, goff, bincnt);
    bin_kernel<<<NBLK, 256, 0, stream>>>(src, dst, goff, binpair);
    csr_kernel<<<NBINS, 1024, 0, stream>>>(bincnt, binpair, rowptr, csr);
    gather_kernel<<<NBINS * 8, 512, 0, stream>>>(featp, rowptr, csr, eps, hbf);
    mlp_kernel<<<256, 512, 0, stream>>>((const short*)hbf, w1t, w2t, b1, b2, out);
}